// Round 7
// baseline (426.610 us; speedup 1.0000x reference)
//
#include <hip/hip_runtime.h>
#include <math.h>

// Problem constants
#define S_ 500
#define D_ 768
#define K_ 16
#define R_ 256
#define P_ 64
#define NT 12      // 768 / BK, BK = 64
#define NBLK 512u  // mega grid: 2 blocks/CU exact

typedef unsigned short ushort_t;
typedef __attribute__((ext_vector_type(8))) short short8;   // 8 x bf16 (4 VGPRs)
typedef __attribute__((ext_vector_type(4))) float floatx4;  // MFMA accumulator
typedef __attribute__((ext_vector_type(4))) float fx4;      // global fp32 vec load

__device__ inline ushort_t f2bf(float x) {  // fp32 -> bf16, round-nearest-even
  unsigned int u = __float_as_uint(x);
  u += 0x7fffu + ((u >> 16) & 1u);
  return (ushort_t)(u >> 16);
}

// packed fp32x2 -> bf16x2 (RNE), single VALU op
__device__ inline unsigned int cvtpk(float lo, float hi) {
  unsigned int r;
  asm("v_cvt_pk_bf16_f32 %0, %1, %2" : "=v"(r) : "v"(lo), "v"(hi));
  return r;
}

#define GLD_LDS16(g, l)                                                        \
  __builtin_amdgcn_global_load_lds(                                            \
      (const __attribute__((address_space(1))) void*)(g),                      \
      (__attribute__((address_space(3))) void*)(l), 16, 0, 0)

// raw barrier / fine-grained vmcnt (phase-2 mm1 pattern, proven r0-r5)
#define ASM_BARRIER asm volatile("s_barrier" ::: "memory")
#define WAIT_VM6 asm volatile("s_waitcnt vmcnt(6)" ::: "memory")
#define WAIT_VM0 asm volatile("s_waitcnt vmcnt(0)" ::: "memory")

// phase-1 mm0 schedule primitives (proven r5)
#define CFENCE asm volatile("" ::: "memory")
#define BARRIER_SYNC                                                           \
  do { CFENCE; __builtin_amdgcn_s_barrier(); CFENCE; } while (0)
#define WAIT_VM20_F                                                            \
  do { asm volatile("s_waitcnt vmcnt(20)" ::: "memory");                       \
       __builtin_amdgcn_sched_barrier(0); } while (0)
#define WAIT_VM0_F                                                             \
  do { asm volatile("s_waitcnt vmcnt(0)" ::: "memory");                        \
       __builtin_amdgcn_sched_barrier(0); } while (0)
#define WAIT_LGKM0_F                                                           \
  do { asm volatile("s_waitcnt lgkmcnt(0)" ::: "memory");                      \
       __builtin_amdgcn_sched_barrier(0); } while (0)

// ---------------------------------------------------------------------------
// software grid barrier (graph-capturable; no cooperative launch needed).
// Correctness chain: __syncthreads() drains vmcnt(0) -> all waves' stores are
// in this XCD's L2; tid0 __threadfence() (agent release) writes back L2;
// device-scope atomicAdd arrives; last block release-stores flag; everyone
// spins with ACQUIRE agent loads (cache-inv per AMDGPU memory model) and a
// trailing __threadfence() before __syncthreads releases the block.
// One counter+flag pair PER PHASE (no reuse -> no generation race); zeroed by
// a hipMemsetAsync graph node before the kernel each replay.
// Deadlock-safe: __launch_bounds__(256,2) + 64 KB LDS guarantee 2 blocks/CU,
// so all 512 blocks are co-resident.
// ---------------------------------------------------------------------------
__device__ __forceinline__ void grid_barrier(unsigned int* bar, int phase) {
  __syncthreads();  // drains vmcnt/lgkm; all block's stores now in L2
  if (threadIdx.x == 0) {
    unsigned int* cnt = bar + phase * 16;        // 64 B apart
    unsigned int* flg = bar + phase * 16 + 8;
    __threadfence();  // agent release: L2 writeback of this block's stores
    unsigned int prev = __hip_atomic_fetch_add(cnt, 1u, __ATOMIC_ACQ_REL,
                                               __HIP_MEMORY_SCOPE_AGENT);
    if (prev == NBLK - 1u)
      __hip_atomic_store(flg, 1u, __ATOMIC_RELEASE, __HIP_MEMORY_SCOPE_AGENT);
    while (__hip_atomic_load(flg, __ATOMIC_ACQUIRE,
                             __HIP_MEMORY_SCOPE_AGENT) == 0u)
      __builtin_amdgcn_s_sleep(2);
    __threadfence();  // acquire side: invalidate stale cache lines
  }
  __syncthreads();
}

// LDS overlays (max 64 KB = phase-1)
struct P1 { ushort_t As[2][2][128 * 32]; ushort_t Bs[2][2][128 * 32]; };  // 64 KB
struct P2 { ushort_t As[2][2][128 * 32]; ushort_t Bs[2][2][64 * 32]; };   // 48 KB
struct P3 { int b1[P_]; int b2[P_]; int len1, len2; float wmx[4][K_]; float wsum[4][K_]; };

// ---------------------------------------------------------------------------
// mega: one regular launch, 512 blocks x 256 threads (2 blocks/CU exact).
//   0: prep  WE fp32 -> WEb bf16 [512][768]         (jobs 0..383)
//   1: mm0_fused proj = WEb @ W (fp32 B, fused cvt)  (jobs 0..383, r5 body)
//   2: mm1   G = projb @ WEb^T                       (jobs 0..511, r5 body)
//   3: lse   out[r][k] = logsumexp gather            (jobs 0..255)
// Replaces 4 launches + 3 inter-kernel drains with 3 in-kernel grid barriers.
// ---------------------------------------------------------------------------
__global__ __launch_bounds__(256, 2) void mega(
    const float* __restrict__ WE, const float* __restrict__ Wf,
    const int* __restrict__ idx1, const int* __restrict__ idx2,
    const float* __restrict__ mask1, const float* __restrict__ mask2,
    ushort_t* __restrict__ WEb, ushort_t* __restrict__ projb,
    ushort_t* __restrict__ G, float* __restrict__ out,
    unsigned int* __restrict__ bar) {
  __shared__ __align__(16) unsigned char smem[sizeof(P1)];
  P1& s1 = *reinterpret_cast<P1*>(smem);
  P2& s2 = *reinterpret_cast<P2*>(smem);
  P3& s3 = *reinterpret_cast<P3*>(smem);
  const int wid = blockIdx.x;
  const int tid = threadIdx.x;
  const int wave = tid >> 6, lane = tid & 63;
  const int col = lane & 15, quad = lane >> 4;

  // ===== phase 0: prep (384 jobs; 1-D wid == old blockIdx.x) =====
  if (wid < 384) {
    int gid = wid * 256 + tid;  // 98304 threads, 4 elems each
    int row = gid / 192;        // 192 float4 per row
    ushort4 o = {0, 0, 0, 0};
    if (row < S_) {
      float4 v = *(const float4*)(WE + (size_t)gid * 4);
      o.x = f2bf(v.x); o.y = f2bf(v.y); o.z = f2bf(v.z); o.w = f2bf(v.w);
    }
    *(ushort4*)(WEb + (size_t)gid * 4) = o;
  }
  grid_barrier(bar, 0);

  // ===== phase 1: mm0_fused (r5 body; wid -> (96,4) grid) =====
  if (wid < 384) {
    const int m0 = (wid / 96) * 128, n0 = (wid % 96) * 128;
    const int wm = (wave & 1) * 64, wn = (wave >> 1) * 64;

    floatx4 acc[4][4];
#pragma unroll
    for (int i = 0; i < 4; i++)
#pragma unroll
      for (int j = 0; j < 4; j++)
#pragma unroll
        for (int e = 0; e < 4; e++) acc[i][j][e] = 0.f;

    const int srow = wave * 32 + (lane >> 2);  // 16 rows x 16 B per issue
    const int scol = (lane & 3) * 8;
    const ushort_t* ga0 = WEb + (size_t)(m0 + srow) * D_ + scol;
    const int ldsbase = (wave * 32) * 32;

#define ISSUE_A(t_, buf_)                                                      \
  do {                                                                         \
    const ushort_t* ga = ga0 + (t_)*64;                                        \
    GLD_LDS16(ga, &s1.As[buf_][0][ldsbase]);                                   \
    GLD_LDS16(ga + 16 * D_, &s1.As[buf_][0][ldsbase + 16 * 32]);               \
    GLD_LDS16(ga + 32, &s1.As[buf_][1][ldsbase]);                              \
    GLD_LDS16(ga + 32 + 16 * D_, &s1.As[buf_][1][ldsbase + 16 * 32]);          \
  } while (0)

    const int nq = tid & 31;   // row-quad 0..31: rows nq*4+j
    const int dqA = tid >> 5;  // k-quad 0..7
    const float* gwA = Wf + (size_t)(dqA * 4) * 12288 + n0 + nq * 4;
    const float* gwB = gwA + (size_t)32 * 12288;

    fx4 bv[2][4];
#define LOADB(t_)                                                              \
  do {                                                                         \
    _Pragma("unroll") for (int i = 0; i < 4; i++) {                            \
      bv[0][i] = *(const fx4*)(gwA + (size_t)((t_)*64 + i) * 12288);           \
      bv[1][i] = *(const fx4*)(gwB + (size_t)((t_)*64 + i) * 12288);           \
    }                                                                          \
  } while (0)

#define WRITEB(buf_)                                                           \
  do {                                                                         \
    _Pragma("unroll") for (int h = 0; h < 2; h++)                              \
    _Pragma("unroll") for (int j = 0; j < 4; j++) {                            \
      int row = nq * 4 + j;                                                    \
      uint2 w;                                                                 \
      w.x = cvtpk(bv[h][0][j], bv[h][1][j]);                                   \
      w.y = cvtpk(bv[h][2][j], bv[h][3][j]);                                   \
      *(uint2*)((char*)&s1.Bs[buf_][h][0] +                                    \
                ((row * 64 + dqA * 8) ^ ((nq & 15) << 4))) = w;                \
    }                                                                          \
  } while (0)

    LOADB(0);
    ISSUE_A(0, 0);
    WRITEB(0);  // compiler vmcnt drains bv(0); A(0)'s 4 stay in flight
    WAIT_LGKM0_F;
    for (int t = 0; t < NT; ++t) {
      const int cur = t & 1;
      if (t + 1 < NT) {
        LOADB(t + 1);             // +16
        ISSUE_A(t + 1, cur ^ 1);  // +4 -> outstanding = A(t)4(oldest) + 20
        WAIT_VM20_F;              // FIFO retire: drains exactly own A(t)
      } else {
        WAIT_VM0_F;
      }
      BARRIER_SYNC;
#pragma unroll
      for (int s = 0; s < 2; ++s) {
        short8 a[4], b[4];
#pragma unroll
        for (int i = 0; i < 4; i++)
          a[i] = *(const short8*)&s1.As[cur][s][(wm + i * 16 + col) * 32 + quad * 8];
#pragma unroll
        for (int j = 0; j < 4; j++) {
          int row = wn + j * 16 + col;
          b[j] = *(const short8*)((const char*)&s1.Bs[cur][s][0] +
                                  ((row * 64 + quad * 16) ^ (((row >> 2) & 15) << 4)));
        }
#pragma unroll
        for (int i = 0; i < 4; i++)
#pragma unroll
          for (int j = 0; j < 4; j++)
            acc[i][j] = __builtin_amdgcn_mfma_f32_16x16x32_bf16(b[j], a[i], acc[i][j], 0, 0, 0);
      }
      if (t + 1 < NT) {
        WRITEB(cur ^ 1);  // compiler vmcnt(4) for bv(t+1); A(t+1) stays flying
        WAIT_LGKM0_F;
      }
      BARRIER_SYNC;
    }
#undef ISSUE_A
#undef LOADB
#undef WRITEB

#pragma unroll
    for (int i = 0; i < 4; i++) {
      int m = m0 + wm + i * 16 + col;
#pragma unroll
      for (int j = 0; j < 4; j++) {
        int n = n0 + wn + j * 16 + quad * 4;
        ushort4 o;
        o.x = f2bf(acc[i][j][0]); o.y = f2bf(acc[i][j][1]);
        o.z = f2bf(acc[i][j][2]); o.w = f2bf(acc[i][j][3]);
        *(ushort4*)(projb + (size_t)m * 12288 + n) = o;
      }
    }
  }
  grid_barrier(bar, 1);

  // ===== phase 2: mm1 (512 jobs; r5 body incl XCD remap; vmcnt=0 at entry) ==
  {
    const int lin = wid;
    const int yb = ((lin & 7) << 3) | (lin >> 6);
    const int xb = (lin >> 3) & 7;
    const int m0 = yb * 128, n0 = xb * 64;
    const int wm = (wave & 1) * 64, wn = (wave >> 1) * 32;

    floatx4 acc[4][2];
#pragma unroll
    for (int i = 0; i < 4; i++)
#pragma unroll
      for (int j = 0; j < 2; j++)
#pragma unroll
        for (int e = 0; e < 4; e++) acc[i][j][e] = 0.f;

    const int lrow = lane >> 2, scol = (lane & 3) * 8;
    const ushort_t* ga0 = projb + (size_t)(m0 + wave * 32 + lrow) * D_ + scol;
    const ushort_t* gb0 = WEb + (size_t)(n0 + wave * 16 + lrow) * D_ + scol;
    const int aoff = (wave * 32) * 32;
    const int boff = (wave * 16) * 32;

#define ISSUE_TILE1(t_, buf_)                                                  \
  do {                                                                         \
    _Pragma("unroll") for (int s_ = 0; s_ < 2; s_++) {                         \
      const ushort_t* ga = ga0 + (t_)*64 + s_ * 32;                            \
      const ushort_t* gb = gb0 + (t_)*64 + s_ * 32;                            \
      GLD_LDS16(ga, &s2.As[buf_][s_][aoff]);                                   \
      GLD_LDS16(ga + 16 * D_, &s2.As[buf_][s_][aoff + 16 * 32]);               \
      GLD_LDS16(gb, &s2.Bs[buf_][s_][boff]);                                   \
    }                                                                          \
  } while (0)

    ISSUE_TILE1(0, 0);
    for (int t = 0; t < NT; ++t) {
      const int cur = t & 1;
      if (t + 1 < NT) {
        ISSUE_TILE1(t + 1, cur ^ 1);
        WAIT_VM6;
      } else {
        WAIT_VM0;
      }
      ASM_BARRIER;
#pragma unroll
      for (int s = 0; s < 2; ++s) {
        short8 a[4], b[2];
#pragma unroll
        for (int i = 0; i < 4; i++)
          a[i] = *(const short8*)&s2.As[cur][s][(wm + i * 16 + col) * 32 + quad * 8];
#pragma unroll
        for (int j = 0; j < 2; j++)
          b[j] = *(const short8*)&s2.Bs[cur][s][(wn + j * 16 + col) * 32 + quad * 8];
#pragma unroll
        for (int i = 0; i < 4; i++)
#pragma unroll
          for (int j = 0; j < 2; j++)
            acc[i][j] = __builtin_amdgcn_mfma_f32_16x16x32_bf16(a[i], b[j], acc[i][j], 0, 0, 0);
      }
      ASM_BARRIER;
    }
#undef ISSUE_TILE1

#pragma unroll
    for (int i = 0; i < 4; i++) {
      int s1r = (m0 + wm + i * 16) >> 4;
#pragma unroll
      for (int j = 0; j < 2; j++) {
        int s2c = n0 + wn + j * 16 + col;
        if (s1r < S_ && s2c < S_) {
          ushort4 o;
          o.x = f2bf(acc[i][j][0]); o.y = f2bf(acc[i][j][1]);
          o.z = f2bf(acc[i][j][2]); o.w = f2bf(acc[i][j][3]);
          *(ushort4*)(G + (((size_t)s1r * S_ + s2c) << 4) + quad * 4) = o;
        }
      }
    }
  }
  grid_barrier(bar, 2);

  // ===== phase 3: lse (256 jobs, 256 threads) =====
  if (wid < R_) {
    const int r = wid;
    if (tid < 64) {
      float mv = mask1[r * P_ + tid];
      unsigned long long bal = __ballot(mv > 0.5f);
      if (tid == 0) s3.len1 = (int)__popcll(bal);
      s3.b1[tid] = idx1[r * P_ + tid] * (S_ * K_);
    } else if (tid < 128) {
      int q = tid - 64;
      float mv = mask2[r * P_ + q];
      unsigned long long bal = __ballot(mv > 0.5f);
      if (q == 0) s3.len2 = (int)__popcll(bal);
      s3.b2[q] = idx2[r * P_ + q] * K_;
    }
    __syncthreads();
    const int len2 = s3.len2;
    const int total = s3.len1 * len2;

    float m[K_], s[K_];
#pragma unroll
    for (int k = 0; k < K_; k++) { m[k] = -3.0e38f; s[k] = 0.f; }

    for (int i = tid; i < total; i += 256) {
      int p = i / len2;
      int q = i - p * len2;
      const uint4* g4 = (const uint4*)(G + s3.b1[p] + s3.b2[q]);  // 32 B
      uint4 w0 = g4[0], w1 = g4[1];
      unsigned int uu[8] = {w0.x, w0.y, w0.z, w0.w, w1.x, w1.y, w1.z, w1.w};
      float z[K_];
#pragma unroll
      for (int h = 0; h < 8; h++) {
        z[2 * h + 0] = __uint_as_float(uu[h] << 16);
        z[2 * h + 1] = __uint_as_float(uu[h] & 0xffff0000u);
      }
#pragma unroll
      for (int k = 0; k < K_; k++) {
        float d = z[k] - m[k];
        float e = __expf(-fabsf(d));
        bool up = d > 0.f;
        s[k] = up ? __fmaf_rn(s[k], e, 1.f) : (s[k] + e);
        m[k] = up ? z[k] : m[k];
      }
    }

#pragma unroll
    for (int off = 1; off < 64; off <<= 1) {
#pragma unroll
      for (int k = 0; k < K_; k++) {
        float mo = __shfl_xor(m[k], off, 64);
        float so = __shfl_xor(s[k], off, 64);
        float d = mo - m[k];
        float e = __expf(-fabsf(d));
        bool up = d > 0.f;
        s[k] = up ? __fmaf_rn(s[k], e, so) : __fmaf_rn(so, e, s[k]);
        m[k] = up ? mo : m[k];
      }
    }
    if (lane == 0) {
#pragma unroll
      for (int k = 0; k < K_; k++) { s3.wmx[wave][k] = m[k]; s3.wsum[wave][k] = s[k]; }
    }
    __syncthreads();
    if (tid < K_) {
      float M = -3.0e38f, Ssum = 0.f;
#pragma unroll
      for (int w = 0; w < 4; w++) {
        float mo = s3.wmx[w][tid], so = s3.wsum[w][tid];
        float d = mo - M;
        float e = __expf(-fabsf(d));
        bool up = d > 0.f;
        Ssum = up ? __fmaf_rn(Ssum, e, so) : __fmaf_rn(so, e, Ssum);
        M = up ? mo : M;
      }
      out[r * K_ + tid] = M + __logf(Ssum);
    }
  }
}

// ---------------------------------------------------------------------------
extern "C" void kernel_launch(void* const* d_in, const int* in_sizes, int n_in,
                              void* d_out, int out_size, void* d_ws, size_t ws_size,
                              hipStream_t stream) {
  const float* WE    = (const float*)d_in[0];  // [500][768]
  const float* Wf    = (const float*)d_in[1];  // [768][16][768]
  const int*   idx1  = (const int*)d_in[2];
  const int*   idx2  = (const int*)d_in[3];
  const float* mask1 = (const float*)d_in[4];
  const float* mask2 = (const float*)d_in[5];
  float* out = (float*)d_out;                  // [256][16]

  // workspace: WEb [512][768] bf16 | projb [512][12288] bf16 (== [8192][768])
  //            | G [500][500][16] bf16 (~21.4 MB) | barrier block @ +32 MB
  ushort_t* WEb   = (ushort_t*)d_ws;
  ushort_t* projb = WEb + (size_t)512 * 768;
  ushort_t* G     = projb + (size_t)512 * 12288;
  unsigned int* bar = (unsigned int*)((char*)d_ws + (size_t)(32u << 20));

  // zero the 3 barrier counter/flag pairs (re-zeroed on every graph replay,
  // ordered before the kernel on this stream).
  hipMemsetAsync(bar, 0, 256, stream);
  mega<<<NBLK, 256, 0, stream>>>(WE, Wf, idx1, idx2, mask1, mask2,
                                 WEb, projb, G, out, bar);
}

// Round 8
// 247.763 us; speedup vs baseline: 1.7218x; 1.7218x over previous
//
#include <hip/hip_runtime.h>
#include <math.h>

// Problem constants
#define S_ 500
#define D_ 768
#define K_ 16
#define R_ 256
#define P_ 64
#define NT 12      // 768 / BK, BK = 64
#define NBLK 512u  // mega grid: 2 blocks/CU exact

typedef unsigned short ushort_t;
typedef __attribute__((ext_vector_type(8))) short short8;   // 8 x bf16 (4 VGPRs)
typedef __attribute__((ext_vector_type(4))) float floatx4;  // MFMA accumulator
typedef __attribute__((ext_vector_type(4))) float fx4;      // global fp32 vec load

__device__ inline ushort_t f2bf(float x) {  // fp32 -> bf16, round-nearest-even
  unsigned int u = __float_as_uint(x);
  u += 0x7fffu + ((u >> 16) & 1u);
  return (ushort_t)(u >> 16);
}

// packed fp32x2 -> bf16x2 (RNE), single VALU op
__device__ inline unsigned int cvtpk(float lo, float hi) {
  unsigned int r;
  asm("v_cvt_pk_bf16_f32 %0, %1, %2" : "=v"(r) : "v"(lo), "v"(hi));
  return r;
}

#define GLD_LDS16(g, l)                                                        \
  __builtin_amdgcn_global_load_lds(                                            \
      (const __attribute__((address_space(1))) void*)(g),                      \
      (__attribute__((address_space(3))) void*)(l), 16, 0, 0)

// raw barrier / fine-grained vmcnt (phase-2 mm1 pattern, proven r0-r5)
#define ASM_BARRIER asm volatile("s_barrier" ::: "memory")
#define WAIT_VM6 asm volatile("s_waitcnt vmcnt(6)" ::: "memory")
#define WAIT_VM0 asm volatile("s_waitcnt vmcnt(0)" ::: "memory")

// phase-1 mm0 schedule primitives (proven r5)
#define CFENCE asm volatile("" ::: "memory")
#define BARRIER_SYNC                                                           \
  do { CFENCE; __builtin_amdgcn_s_barrier(); CFENCE; } while (0)
#define WAIT_VM20_F                                                            \
  do { asm volatile("s_waitcnt vmcnt(20)" ::: "memory");                       \
       __builtin_amdgcn_sched_barrier(0); } while (0)
#define WAIT_VM0_F                                                             \
  do { asm volatile("s_waitcnt vmcnt(0)" ::: "memory");                        \
       __builtin_amdgcn_sched_barrier(0); } while (0)
#define WAIT_LGKM0_F                                                           \
  do { asm volatile("s_waitcnt lgkmcnt(0)" ::: "memory");                      \
       __builtin_amdgcn_sched_barrier(0); } while (0)

// ---------------------------------------------------------------------------
// software grid barrier, v2 (r7's v1 spun on ACQUIRE agent loads -> one
// full-L2 buffer_inv PER POLL ITERATION x 512 blocks = ~110 us/barrier,
// 96% idle kernel).  Fix:
//  - release: counter fetch_add with __ATOMIC_RELEASE (one buffer_wbl2 per
//    block publishes this block's phase stores to LLC).
//  - spin: RELAXED agent loads (sc1 -> LLC-coherent reads, NO cache inv);
//    every 64 polls a fetch_add(0) RMW fallback (RMWs always reach the
//    coherence point -> progress guaranteed even if a relaxed load could be
//    served stale).
//  - acquire: ONE __ATOMIC_ACQUIRE load after the spin exits (single
//    buffer_inv per block per barrier).
// Co-residency of all 512 blocks proven by r7 passing.  Counters zeroed by a
// hipMemsetAsync graph node before the kernel each replay.
// ---------------------------------------------------------------------------
__device__ __forceinline__ void grid_barrier(unsigned int* bar, int phase) {
  __syncthreads();  // drains vmcnt/lgkm; all block's stores issued
  if (threadIdx.x == 0) {
    unsigned int* cnt = bar + phase * 32;  // 128 B apart per phase
    unsigned int* flg = cnt + 16;
    unsigned int prev = __hip_atomic_fetch_add(cnt, 1u, __ATOMIC_RELEASE,
                                               __HIP_MEMORY_SCOPE_AGENT);
    if (prev == NBLK - 1u)
      __hip_atomic_store(flg, 1u, __ATOMIC_RELEASE, __HIP_MEMORY_SCOPE_AGENT);
    int it = 0;
    while (__hip_atomic_load(flg, __ATOMIC_RELAXED,
                             __HIP_MEMORY_SCOPE_AGENT) == 0u) {
      __builtin_amdgcn_s_sleep(4);
      if ((++it & 63) == 0)
        (void)__hip_atomic_fetch_add(flg, 0u, __ATOMIC_RELAXED,
                                     __HIP_MEMORY_SCOPE_AGENT);
    }
    (void)__hip_atomic_load(flg, __ATOMIC_ACQUIRE, __HIP_MEMORY_SCOPE_AGENT);
  }
  __syncthreads();
}

// LDS overlays (max 64 KB = phase-1)
struct P1 { ushort_t As[2][2][128 * 32]; ushort_t Bs[2][2][128 * 32]; };  // 64 KB
struct P2 { ushort_t As[2][2][128 * 32]; ushort_t Bs[2][2][64 * 32]; };   // 48 KB
struct P3 { int b1[P_]; int b2[P_]; int len1, len2; float wmx[4][K_]; float wsum[4][K_]; };

// ---------------------------------------------------------------------------
// mega: one regular launch, 512 blocks x 256 threads (2 blocks/CU exact).
//   0: prep  WE fp32 -> WEb bf16 [512][768]         (jobs 0..383)
//   1: mm0_fused proj = WEb @ W (fp32 B, fused cvt)  (jobs 0..383, r5 body)
//   2: mm1   G = projb @ WEb^T                       (jobs 0..511, r5 body)
//   3: lse   out[r][k] = logsumexp gather            (jobs 0..255)
// Replaces 4 launches + 3 inter-kernel drains with 3 in-kernel grid barriers.
// ---------------------------------------------------------------------------
__global__ __launch_bounds__(256, 2) void mega(
    const float* __restrict__ WE, const float* __restrict__ Wf,
    const int* __restrict__ idx1, const int* __restrict__ idx2,
    const float* __restrict__ mask1, const float* __restrict__ mask2,
    ushort_t* __restrict__ WEb, ushort_t* __restrict__ projb,
    ushort_t* __restrict__ G, float* __restrict__ out,
    unsigned int* __restrict__ bar) {
  __shared__ __align__(16) unsigned char smem[sizeof(P1)];
  P1& s1 = *reinterpret_cast<P1*>(smem);
  P2& s2 = *reinterpret_cast<P2*>(smem);
  P3& s3 = *reinterpret_cast<P3*>(smem);
  const int wid = blockIdx.x;
  const int tid = threadIdx.x;
  const int wave = tid >> 6, lane = tid & 63;
  const int col = lane & 15, quad = lane >> 4;

  // ===== phase 0: prep (384 jobs; 1-D wid == old blockIdx.x) =====
  if (wid < 384) {
    int gid = wid * 256 + tid;  // 98304 threads, 4 elems each
    int row = gid / 192;        // 192 float4 per row
    ushort4 o = {0, 0, 0, 0};
    if (row < S_) {
      float4 v = *(const float4*)(WE + (size_t)gid * 4);
      o.x = f2bf(v.x); o.y = f2bf(v.y); o.z = f2bf(v.z); o.w = f2bf(v.w);
    }
    *(ushort4*)(WEb + (size_t)gid * 4) = o;
  }
  grid_barrier(bar, 0);

  // ===== phase 1: mm0_fused (r5 body; wid -> (96,4) grid) =====
  if (wid < 384) {
    const int m0 = (wid / 96) * 128, n0 = (wid % 96) * 128;
    const int wm = (wave & 1) * 64, wn = (wave >> 1) * 64;

    floatx4 acc[4][4];
#pragma unroll
    for (int i = 0; i < 4; i++)
#pragma unroll
      for (int j = 0; j < 4; j++)
#pragma unroll
        for (int e = 0; e < 4; e++) acc[i][j][e] = 0.f;

    const int srow = wave * 32 + (lane >> 2);  // 16 rows x 16 B per issue
    const int scol = (lane & 3) * 8;
    const ushort_t* ga0 = WEb + (size_t)(m0 + srow) * D_ + scol;
    const int ldsbase = (wave * 32) * 32;

#define ISSUE_A(t_, buf_)                                                      \
  do {                                                                         \
    const ushort_t* ga = ga0 + (t_)*64;                                        \
    GLD_LDS16(ga, &s1.As[buf_][0][ldsbase]);                                   \
    GLD_LDS16(ga + 16 * D_, &s1.As[buf_][0][ldsbase + 16 * 32]);               \
    GLD_LDS16(ga + 32, &s1.As[buf_][1][ldsbase]);                              \
    GLD_LDS16(ga + 32 + 16 * D_, &s1.As[buf_][1][ldsbase + 16 * 32]);          \
  } while (0)

    const int nq = tid & 31;   // row-quad 0..31: rows nq*4+j
    const int dqA = tid >> 5;  // k-quad 0..7
    const float* gwA = Wf + (size_t)(dqA * 4) * 12288 + n0 + nq * 4;
    const float* gwB = gwA + (size_t)32 * 12288;

    fx4 bv[2][4];
#define LOADB(t_)                                                              \
  do {                                                                         \
    _Pragma("unroll") for (int i = 0; i < 4; i++) {                            \
      bv[0][i] = *(const fx4*)(gwA + (size_t)((t_)*64 + i) * 12288);           \
      bv[1][i] = *(const fx4*)(gwB + (size_t)((t_)*64 + i) * 12288);           \
    }                                                                          \
  } while (0)

#define WRITEB(buf_)                                                           \
  do {                                                                         \
    _Pragma("unroll") for (int h = 0; h < 2; h++)                              \
    _Pragma("unroll") for (int j = 0; j < 4; j++) {                            \
      int row = nq * 4 + j;                                                    \
      uint2 w;                                                                 \
      w.x = cvtpk(bv[h][0][j], bv[h][1][j]);                                   \
      w.y = cvtpk(bv[h][2][j], bv[h][3][j]);                                   \
      *(uint2*)((char*)&s1.Bs[buf_][h][0] +                                    \
                ((row * 64 + dqA * 8) ^ ((nq & 15) << 4))) = w;                \
    }                                                                          \
  } while (0)

    LOADB(0);
    ISSUE_A(0, 0);
    WRITEB(0);  // compiler vmcnt drains bv(0); A(0)'s 4 stay in flight
    WAIT_LGKM0_F;
    for (int t = 0; t < NT; ++t) {
      const int cur = t & 1;
      if (t + 1 < NT) {
        LOADB(t + 1);             // +16
        ISSUE_A(t + 1, cur ^ 1);  // +4 -> outstanding = A(t)4(oldest) + 20
        WAIT_VM20_F;              // FIFO retire: drains exactly own A(t)
      } else {
        WAIT_VM0_F;
      }
      BARRIER_SYNC;
#pragma unroll
      for (int s = 0; s < 2; ++s) {
        short8 a[4], b[4];
#pragma unroll
        for (int i = 0; i < 4; i++)
          a[i] = *(const short8*)&s1.As[cur][s][(wm + i * 16 + col) * 32 + quad * 8];
#pragma unroll
        for (int j = 0; j < 4; j++) {
          int row = wn + j * 16 + col;
          b[j] = *(const short8*)((const char*)&s1.Bs[cur][s][0] +
                                  ((row * 64 + quad * 16) ^ (((row >> 2) & 15) << 4)));
        }
#pragma unroll
        for (int i = 0; i < 4; i++)
#pragma unroll
          for (int j = 0; j < 4; j++)
            acc[i][j] = __builtin_amdgcn_mfma_f32_16x16x32_bf16(b[j], a[i], acc[i][j], 0, 0, 0);
      }
      if (t + 1 < NT) {
        WRITEB(cur ^ 1);  // compiler vmcnt(4) for bv(t+1); A(t+1) stays flying
        WAIT_LGKM0_F;
      }
      BARRIER_SYNC;
    }
#undef ISSUE_A
#undef LOADB
#undef WRITEB

#pragma unroll
    for (int i = 0; i < 4; i++) {
      int m = m0 + wm + i * 16 + col;
#pragma unroll
      for (int j = 0; j < 4; j++) {
        int n = n0 + wn + j * 16 + quad * 4;
        ushort4 o;
        o.x = f2bf(acc[i][j][0]); o.y = f2bf(acc[i][j][1]);
        o.z = f2bf(acc[i][j][2]); o.w = f2bf(acc[i][j][3]);
        *(ushort4*)(projb + (size_t)m * 12288 + n) = o;
      }
    }
  }
  grid_barrier(bar, 1);

  // ===== phase 2: mm1 (512 jobs; r5 body incl XCD remap; vmcnt=0 at entry) ==
  {
    const int lin = wid;
    const int yb = ((lin & 7) << 3) | (lin >> 6);
    const int xb = (lin >> 3) & 7;
    const int m0 = yb * 128, n0 = xb * 64;
    const int wm = (wave & 1) * 64, wn = (wave >> 1) * 32;

    floatx4 acc[4][2];
#pragma unroll
    for (int i = 0; i < 4; i++)
#pragma unroll
      for (int j = 0; j < 2; j++)
#pragma unroll
        for (int e = 0; e < 4; e++) acc[i][j][e] = 0.f;

    const int lrow = lane >> 2, scol = (lane & 3) * 8;
    const ushort_t* ga0 = projb + (size_t)(m0 + wave * 32 + lrow) * D_ + scol;
    const ushort_t* gb0 = WEb + (size_t)(n0 + wave * 16 + lrow) * D_ + scol;
    const int aoff = (wave * 32) * 32;
    const int boff = (wave * 16) * 32;

#define ISSUE_TILE1(t_, buf_)                                                  \
  do {                                                                         \
    _Pragma("unroll") for (int s_ = 0; s_ < 2; s_++) {                         \
      const ushort_t* ga = ga0 + (t_)*64 + s_ * 32;                            \
      const ushort_t* gb = gb0 + (t_)*64 + s_ * 32;                            \
      GLD_LDS16(ga, &s2.As[buf_][s_][aoff]);                                   \
      GLD_LDS16(ga + 16 * D_, &s2.As[buf_][s_][aoff + 16 * 32]);               \
      GLD_LDS16(gb, &s2.Bs[buf_][s_][boff]);                                   \
    }                                                                          \
  } while (0)

    ISSUE_TILE1(0, 0);
    for (int t = 0; t < NT; ++t) {
      const int cur = t & 1;
      if (t + 1 < NT) {
        ISSUE_TILE1(t + 1, cur ^ 1);
        WAIT_VM6;
      } else {
        WAIT_VM0;
      }
      ASM_BARRIER;
#pragma unroll
      for (int s = 0; s < 2; ++s) {
        short8 a[4], b[2];
#pragma unroll
        for (int i = 0; i < 4; i++)
          a[i] = *(const short8*)&s2.As[cur][s][(wm + i * 16 + col) * 32 + quad * 8];
#pragma unroll
        for (int j = 0; j < 2; j++)
          b[j] = *(const short8*)&s2.Bs[cur][s][(wn + j * 16 + col) * 32 + quad * 8];
#pragma unroll
        for (int i = 0; i < 4; i++)
#pragma unroll
          for (int j = 0; j < 2; j++)
            acc[i][j] = __builtin_amdgcn_mfma_f32_16x16x32_bf16(a[i], b[j], acc[i][j], 0, 0, 0);
      }
      ASM_BARRIER;
    }
#undef ISSUE_TILE1

#pragma unroll
    for (int i = 0; i < 4; i++) {
      int s1r = (m0 + wm + i * 16) >> 4;
#pragma unroll
      for (int j = 0; j < 2; j++) {
        int s2c = n0 + wn + j * 16 + col;
        if (s1r < S_ && s2c < S_) {
          ushort4 o;
          o.x = f2bf(acc[i][j][0]); o.y = f2bf(acc[i][j][1]);
          o.z = f2bf(acc[i][j][2]); o.w = f2bf(acc[i][j][3]);
          *(ushort4*)(G + (((size_t)s1r * S_ + s2c) << 4) + quad * 4) = o;
        }
      }
    }
  }
  grid_barrier(bar, 2);

  // ===== phase 3: lse (256 jobs, 256 threads) =====
  if (wid < R_) {
    const int r = wid;
    if (tid < 64) {
      float mv = mask1[r * P_ + tid];
      unsigned long long bal = __ballot(mv > 0.5f);
      if (tid == 0) s3.len1 = (int)__popcll(bal);
      s3.b1[tid] = idx1[r * P_ + tid] * (S_ * K_);
    } else if (tid < 128) {
      int q = tid - 64;
      float mv = mask2[r * P_ + q];
      unsigned long long bal = __ballot(mv > 0.5f);
      if (q == 0) s3.len2 = (int)__popcll(bal);
      s3.b2[q] = idx2[r * P_ + q] * K_;
    }
    __syncthreads();
    const int len2 = s3.len2;
    const int total = s3.len1 * len2;

    float m[K_], s[K_];
#pragma unroll
    for (int k = 0; k < K_; k++) { m[k] = -3.0e38f; s[k] = 0.f; }

    for (int i = tid; i < total; i += 256) {
      int p = i / len2;
      int q = i - p * len2;
      const uint4* g4 = (const uint4*)(G + s3.b1[p] + s3.b2[q]);  // 32 B
      uint4 w0 = g4[0], w1 = g4[1];
      unsigned int uu[8] = {w0.x, w0.y, w0.z, w0.w, w1.x, w1.y, w1.z, w1.w};
      float z[K_];
#pragma unroll
      for (int h = 0; h < 8; h++) {
        z[2 * h + 0] = __uint_as_float(uu[h] << 16);
        z[2 * h + 1] = __uint_as_float(uu[h] & 0xffff0000u);
      }
#pragma unroll
      for (int k = 0; k < K_; k++) {
        float d = z[k] - m[k];
        float e = __expf(-fabsf(d));
        bool up = d > 0.f;
        s[k] = up ? __fmaf_rn(s[k], e, 1.f) : (s[k] + e);
        m[k] = up ? z[k] : m[k];
      }
    }

#pragma unroll
    for (int off = 1; off < 64; off <<= 1) {
#pragma unroll
      for (int k = 0; k < K_; k++) {
        float mo = __shfl_xor(m[k], off, 64);
        float so = __shfl_xor(s[k], off, 64);
        float d = mo - m[k];
        float e = __expf(-fabsf(d));
        bool up = d > 0.f;
        s[k] = up ? __fmaf_rn(s[k], e, so) : __fmaf_rn(so, e, s[k]);
        m[k] = up ? mo : m[k];
      }
    }
    if (lane == 0) {
#pragma unroll
      for (int k = 0; k < K_; k++) { s3.wmx[wave][k] = m[k]; s3.wsum[wave][k] = s[k]; }
    }
    __syncthreads();
    if (tid < K_) {
      float M = -3.0e38f, Ssum = 0.f;
#pragma unroll
      for (int w = 0; w < 4; w++) {
        float mo = s3.wmx[w][tid], so = s3.wsum[w][tid];
        float d = mo - M;
        float e = __expf(-fabsf(d));
        bool up = d > 0.f;
        Ssum = up ? __fmaf_rn(Ssum, e, so) : __fmaf_rn(so, e, Ssum);
        M = up ? mo : M;
      }
      out[r * K_ + tid] = M + __logf(Ssum);
    }
  }
}

// ---------------------------------------------------------------------------
extern "C" void kernel_launch(void* const* d_in, const int* in_sizes, int n_in,
                              void* d_out, int out_size, void* d_ws, size_t ws_size,
                              hipStream_t stream) {
  const float* WE    = (const float*)d_in[0];  // [500][768]
  const float* Wf    = (const float*)d_in[1];  // [768][16][768]
  const int*   idx1  = (const int*)d_in[2];
  const int*   idx2  = (const int*)d_in[3];
  const float* mask1 = (const float*)d_in[4];
  const float* mask2 = (const float*)d_in[5];
  float* out = (float*)d_out;                  // [256][16]

  // workspace: WEb [512][768] bf16 | projb [512][12288] bf16 (== [8192][768])
  //            | G [500][500][16] bf16 (~21.4 MB) | barrier block @ +32 MB
  ushort_t* WEb   = (ushort_t*)d_ws;
  ushort_t* projb = WEb + (size_t)512 * 768;
  ushort_t* G     = projb + (size_t)512 * 12288;
  unsigned int* bar = (unsigned int*)((char*)d_ws + (size_t)(32u << 20));

  // zero the 3 barrier counter/flag pairs (re-zeroed on every graph replay,
  // ordered before the kernel on this stream).
  hipMemsetAsync(bar, 0, 512, stream);
  mega<<<NBLK, 256, 0, stream>>>(WE, Wf, idx1, idx2, mask1, mask2,
                                 WEb, projb, G, out, bar);
}

// Round 9
// 155.764 us; speedup vs baseline: 2.7388x; 1.5906x over previous
//
#include <hip/hip_runtime.h>
#include <math.h>

// Problem constants
#define S_ 500
#define D_ 768
#define K_ 16
#define R_ 256
#define P_ 64
#define NT 12  // 768 / BK, BK = 64

typedef unsigned short ushort_t;
typedef __attribute__((ext_vector_type(8))) short short8;   // 8 x bf16 (4 VGPRs)
typedef __attribute__((ext_vector_type(4))) float floatx4;  // MFMA accumulator
typedef __attribute__((ext_vector_type(4))) float fx4;      // global fp32 vec load

__device__ inline ushort_t f2bf(float x) {  // fp32 -> bf16, round-nearest-even
  unsigned int u = __float_as_uint(x);
  u += 0x7fffu + ((u >> 16) & 1u);
  return (ushort_t)(u >> 16);
}

// packed fp32x2 -> bf16x2 (RNE), single VALU op; lo -> low 16 bits (r3-proven)
__device__ inline unsigned int cvtpk(float lo, float hi) {
  unsigned int r;
  asm("v_cvt_pk_bf16_f32 %0, %1, %2" : "=v"(r) : "v"(lo), "v"(hi));
  return r;
}

#define GLD_LDS16(g, l)                                                        \
  __builtin_amdgcn_global_load_lds(                                            \
      (const __attribute__((address_space(1))) void*)(g),                      \
      (__attribute__((address_space(3))) void*)(l), 16, 0, 0)

// ---------------------------------------------------------------------------
// mm0_f: proj = cvt(WE) @ W.  BOTH operands fp32 in HBM, converted to bf16
// during staging (prep kernel eliminated).  Tile 128x128, BK=64 dbuf, 64 KB
// LDS, grid 96x4.  Single-__syncthreads pipeline (r3-proven schedule): loads
// for tile t+1 issue after the barrier and are consumed by the LDS writes
// before the next barrier -> they never cross a barrier, no drain stall.
// A path: ra=tid>>1 owns one row-half: 8 float4 (guarded row<500) -> 16 cvtpk
//   -> 4 ds_write_b128 into As with XOR swizzle byte^((ra&15)<<4) (bijective;
//   write and read at bank floor).  Read applies the same involution.
// B path: r5-proven reg-stage (8 float4, 16 cvtpk, 8 ds_write_b64, XOR
//   ((nq&15)<<4)).
// mfma(b,a): lane regs span 4 consecutive C-cols -> ushort4 stores.
// C = proj bf16 [512][12288] (== proj2d [8192][768]); A-rows >=500 are zero.
// ---------------------------------------------------------------------------
__global__ __launch_bounds__(256, 2) void mm0_f(const float* __restrict__ WE,
                                                const float* __restrict__ Wf,
                                                ushort_t* __restrict__ C) {
  __shared__ ushort_t As[2][2][128 * 32];  // [buf][ksub][row][32k'], 32 KB
  __shared__ ushort_t Bs[2][2][128 * 32];  // 32 KB, XOR-swizzled
  const int tid = threadIdx.x;
  const int wave = tid >> 6, lane = tid & 63;
  const int m0 = blockIdx.y * 128, n0 = blockIdx.x * 128;
  const int wm = (wave & 1) * 64, wn = (wave >> 1) * 64;
  const int col = lane & 15, quad = lane >> 4;

  floatx4 acc[4][4];
#pragma unroll
  for (int i = 0; i < 4; i++)
#pragma unroll
    for (int j = 0; j < 4; j++)
#pragma unroll
      for (int e = 0; e < 4; e++) acc[i][j][e] = 0.f;

  // --- A staging: thread owns (row ra, k-half ka): 32 consecutive fp32 ---
  const int ra = tid >> 1, ka = tid & 1;
  const bool va = (m0 + ra) < S_;
  const fx4* wa = (const fx4*)WE + (size_t)(m0 + ra) * 192 + ka * 8;
  fx4 av[8];
#define LOADA(t_)                                                              \
  do {                                                                         \
    _Pragma("unroll") for (int i = 0; i < 8; i++) {                            \
      if (va) av[i] = wa[(t_)*16 + i];                                         \
      else { av[i][0] = 0.f; av[i][1] = 0.f; av[i][2] = 0.f; av[i][3] = 0.f; } \
    }                                                                          \
  } while (0)

  // As[buf][ka] byte layout: row ra at ra*64, 16-B slot j; XOR ((ra&15)<<4)
#define WRITEA(buf_)                                                           \
  do {                                                                         \
    _Pragma("unroll") for (int j = 0; j < 4; j++) {                            \
      uint4 o;                                                                 \
      o.x = cvtpk(av[2 * j][0], av[2 * j][1]);                                 \
      o.y = cvtpk(av[2 * j][2], av[2 * j][3]);                                 \
      o.z = cvtpk(av[2 * j + 1][0], av[2 * j + 1][1]);                         \
      o.w = cvtpk(av[2 * j + 1][2], av[2 * j + 1][3]);                         \
      *(uint4*)((char*)&As[buf_][ka][0] +                                      \
                ((ra * 64 + j * 16) ^ ((ra & 15) << 4))) = o;                  \
    }                                                                          \
  } while (0)

  // --- B staging: r5-proven. thread owns 4x4 fp32 blocks (dqA,nq), h=0/1 ---
  const int nq = tid & 31;   // row-quad: rows nq*4+j
  const int dqA = tid >> 5;  // k-quad: k'' = dqA*4 + i
  const float* gwA = Wf + (size_t)(dqA * 4) * 12288 + n0 + nq * 4;
  const float* gwB = gwA + (size_t)32 * 12288;
  fx4 bv[2][4];
#define LOADB(t_)                                                              \
  do {                                                                         \
    _Pragma("unroll") for (int i = 0; i < 4; i++) {                            \
      bv[0][i] = *(const fx4*)(gwA + (size_t)((t_)*64 + i) * 12288);           \
      bv[1][i] = *(const fx4*)(gwB + (size_t)((t_)*64 + i) * 12288);           \
    }                                                                          \
  } while (0)

#define WRITEB(buf_)                                                           \
  do {                                                                         \
    _Pragma("unroll") for (int h = 0; h < 2; h++)                              \
    _Pragma("unroll") for (int j = 0; j < 4; j++) {                            \
      int row = nq * 4 + j;                                                    \
      uint2 w;                                                                 \
      w.x = cvtpk(bv[h][0][j], bv[h][1][j]);                                   \
      w.y = cvtpk(bv[h][2][j], bv[h][3][j]);                                   \
      *(uint2*)((char*)&Bs[buf_][h][0] +                                       \
                ((row * 64 + dqA * 8) ^ ((nq & 15) << 4))) = w;                \
    }                                                                          \
  } while (0)

  // prologue: stage tile 0 into buf 0
  LOADA(0);
  LOADB(0);
  WRITEA(0);
  WRITEB(0);
  for (int t = 0; t < NT; ++t) {
    const int cur = t & 1;
    __syncthreads();  // publish writes to buf[cur]; all waves aligned
    if (t + 1 < NT) { LOADA(t + 1); LOADB(t + 1); }  // fly during compute
#pragma unroll
    for (int s = 0; s < 2; ++s) {
      short8 a[4], b[4];
#pragma unroll
      for (int i = 0; i < 4; i++) {
        int row = wm + i * 16 + col;  // row & 15 == col
        a[i] = *(const short8*)((const char*)&As[cur][s][0] +
                                ((row * 64 + quad * 16) ^ (col << 4)));
      }
#pragma unroll
      for (int j = 0; j < 4; j++) {
        int row = wn + j * 16 + col;
        b[j] = *(const short8*)((const char*)&Bs[cur][s][0] +
                                ((row * 64 + quad * 16) ^ (((row >> 2) & 15) << 4)));
      }
#pragma unroll
      for (int i = 0; i < 4; i++)
#pragma unroll
        for (int j = 0; j < 4; j++)
          acc[i][j] = __builtin_amdgcn_mfma_f32_16x16x32_bf16(b[j], a[i], acc[i][j], 0, 0, 0);
    }
    if (t + 1 < NT) {  // write NEXT tile into buf[cur^1]; its readers
      WRITEA(cur ^ 1); // (compute(t-1)) finished before this iter's barrier
      WRITEB(cur ^ 1);
    }
  }
#undef LOADA
#undef WRITEA
#undef LOADB
#undef WRITEB

#pragma unroll
  for (int i = 0; i < 4; i++) {
    int m = m0 + wm + i * 16 + col;
#pragma unroll
    for (int j = 0; j < 4; j++) {
      int n = n0 + wn + j * 16 + quad * 4;
      ushort4 o;
      o.x = f2bf(acc[i][j][0]); o.y = f2bf(acc[i][j][1]);
      o.z = f2bf(acc[i][j][2]); o.w = f2bf(acc[i][j][3]);
      *(ushort4*)(C + (size_t)m * 12288 + n) = o;
    }
  }
}

// ---------------------------------------------------------------------------
// mm1_f: G = projb @ cvt(WE)^T.  A = projb bf16 via proven global_load_lds;
// B = WE fp32 converted inline (guarded rows >=500 -> 0, replacing WEb's
// zero-padding).  Tile 128m x 64n, BK=64 dbuf, 48 KB LDS; grid 8x64 = 512 =
// 2/CU exact; XCD-aware bijective remap (r2-proven).  Single-__syncthreads
// pipeline: gld_lds A(t+1) + B loads issue post-barrier; B writes pre-next-
// barrier; the barrier's implicit vmcnt(0) drains A(t+1) after a full
// compute phase of flight time.
// mfma(a,b): lane regs span k (G's contiguous dim) -> ushort4 scatter into
// bf16 G[s1][s2][16], guarded < 500.
// ---------------------------------------------------------------------------
__global__ __launch_bounds__(256, 2) void mm1_f(const ushort_t* __restrict__ A,
                                                const float* __restrict__ WE,
                                                ushort_t* __restrict__ G) {
  __shared__ ushort_t As[2][2][128 * 32];  // 32 KB
  __shared__ ushort_t Bs[2][2][64 * 32];   // 16 KB
  const int tid = threadIdx.x;
  const int wave = tid >> 6, lane = tid & 63;
  // lin bits [b8..b0]: yb = {b2 b1 b0 b8 b7 b6}, xb = {b5 b4 b3}
  const int lin = blockIdx.x + (blockIdx.y << 3);
  const int yb = ((lin & 7) << 3) | (lin >> 6);
  const int xb = (lin >> 3) & 7;
  const int m0 = yb * 128, n0 = xb * 64;
  const int wm = (wave & 1) * 64, wn = (wave >> 1) * 32;
  const int col = lane & 15, quad = lane >> 4;

  floatx4 acc[4][2];
#pragma unroll
  for (int i = 0; i < 4; i++)
#pragma unroll
    for (int j = 0; j < 2; j++)
#pragma unroll
      for (int e = 0; e < 4; e++) acc[i][j][e] = 0.f;

  // --- A staging: proven gld_lds (projb bf16), 4 issues/thread/tile ---
  const int lrow = lane >> 2, scol = (lane & 3) * 8;
  const ushort_t* ga0 = A + (size_t)(m0 + wave * 32 + lrow) * D_ + scol;
  const int aoff = (wave * 32) * 32;
#define ISSUE_A1(t_, buf_)                                                     \
  do {                                                                         \
    _Pragma("unroll") for (int s_ = 0; s_ < 2; s_++) {                         \
      const ushort_t* ga = ga0 + (t_)*64 + s_ * 32;                            \
      GLD_LDS16(ga, &As[buf_][s_][aoff]);                                      \
      GLD_LDS16(ga + 16 * D_, &As[buf_][s_][aoff + 16 * 32]);                  \
    }                                                                          \
  } while (0)

  // --- B staging: thread owns (row rb, k-quad kq): 16 consecutive fp32 ---
  const int rb = tid >> 2, kq = tid & 3;
  const bool vb = (n0 + rb) < S_;
  const fx4* wb = (const fx4*)WE + (size_t)(n0 + rb) * 192 + kq * 4;
  fx4 bvv[4];
#define LOADB1(t_)                                                             \
  do {                                                                         \
    _Pragma("unroll") for (int i = 0; i < 4; i++) {                            \
      if (vb) bvv[i] = wb[(t_)*16 + i];                                        \
      else { bvv[i][0]=0.f; bvv[i][1]=0.f; bvv[i][2]=0.f; bvv[i][3]=0.f; }     \
    }                                                                          \
  } while (0)

  // Bs[buf][kq>>1] linear (matches proven read path): row rb, 16 bf16 at
  // byte rb*64 + (kq&1)*32
#define WRITEB1(buf_)                                                          \
  do {                                                                         \
    uint4 u0, u1;                                                              \
    u0.x = cvtpk(bvv[0][0], bvv[0][1]); u0.y = cvtpk(bvv[0][2], bvv[0][3]);    \
    u0.z = cvtpk(bvv[1][0], bvv[1][1]); u0.w = cvtpk(bvv[1][2], bvv[1][3]);    \
    u1.x = cvtpk(bvv[2][0], bvv[2][1]); u1.y = cvtpk(bvv[2][2], bvv[2][3]);    \
    u1.z = cvtpk(bvv[3][0], bvv[3][1]); u1.w = cvtpk(bvv[3][2], bvv[3][3]);    \
    char* bp = (char*)&Bs[buf_][kq >> 1][0] + rb * 64 + (kq & 1) * 32;         \
    *(uint4*)bp = u0;                                                          \
    *(uint4*)(bp + 16) = u1;                                                   \
  } while (0)

  LOADB1(0);
  ISSUE_A1(0, 0);
  WRITEB1(0);  // compiler vmcnt drains bvv(0) (oldest 4); A(0) stays flying
  for (int t = 0; t < NT; ++t) {
    const int cur = t & 1;
    __syncthreads();  // implicit vmcnt(0): A(t) landed; Bs[cur] published
    if (t + 1 < NT) {
      LOADB1(t + 1);            // queue: [B(t+1) x4 ...
      ISSUE_A1(t + 1, cur ^ 1); //         ... A(t+1) x4]
    }
#pragma unroll
    for (int s = 0; s < 2; ++s) {
      short8 a[4], b[2];
#pragma unroll
      for (int i = 0; i < 4; i++)
        a[i] = *(const short8*)&As[cur][s][(wm + i * 16 + col) * 32 + quad * 8];
#pragma unroll
      for (int j = 0; j < 2; j++)
        b[j] = *(const short8*)&Bs[cur][s][(wn + j * 16 + col) * 32 + quad * 8];
#pragma unroll
      for (int i = 0; i < 4; i++)
#pragma unroll
        for (int j = 0; j < 2; j++)
          acc[i][j] = __builtin_amdgcn_mfma_f32_16x16x32_bf16(a[i], b[j], acc[i][j], 0, 0, 0);
    }
    if (t + 1 < NT)
      WRITEB1(cur ^ 1);  // compiler vmcnt(4) drains B(t+1); A(t+1) keeps flying
  }
#undef ISSUE_A1
#undef LOADB1
#undef WRITEB1

  // G[s1][s2][16] bf16: m = (s1,k); 16x16 m-tile is one s1, k = quad*4+reg
#pragma unroll
  for (int i = 0; i < 4; i++) {
    int s1 = (m0 + wm + i * 16) >> 4;
#pragma unroll
    for (int j = 0; j < 2; j++) {
      int s2 = n0 + wn + j * 16 + col;
      if (s1 < S_ && s2 < S_) {
        ushort4 o;
        o.x = f2bf(acc[i][j][0]); o.y = f2bf(acc[i][j][1]);
        o.z = f2bf(acc[i][j][2]); o.w = f2bf(acc[i][j][3]);
        *(ushort4*)(G + (((size_t)s1 * S_ + s2) << 4) + quad * 4) = o;
      }
    }
  }
}

// ---------------------------------------------------------------------------
// lse_kernel: out[r][k] = logsumexp over valid (p,q) of G[idx1[r,p]][idx2[r,q]][k]
// One block per r; 512 threads (2 waves/SIMD for LLC-gather latency hiding);
// 1-exp online update (e = exp(-|d|) + select).  (r5-proven, unchanged.)
// ---------------------------------------------------------------------------
__global__ __launch_bounds__(512) void lse_kernel(const ushort_t* __restrict__ G,
                                                  const int* __restrict__ idx1,
                                                  const int* __restrict__ idx2,
                                                  const float* __restrict__ mask1,
                                                  const float* __restrict__ mask2,
                                                  float* __restrict__ out) {
  const int r = blockIdx.x;
  const int tid = threadIdx.x;
  __shared__ int b1[P_], b2[P_];
  __shared__ int s_len1, s_len2;
  __shared__ float wmx[8][K_], wsum[8][K_];

  if (tid < 64) {
    float mv = mask1[r * P_ + tid];
    unsigned long long bal = __ballot(mv > 0.5f);
    if (tid == 0) s_len1 = (int)__popcll(bal);
    b1[tid] = idx1[r * P_ + tid] * (S_ * K_);
  } else if (tid < 128) {
    int q = tid - 64;
    float mv = mask2[r * P_ + q];
    unsigned long long bal = __ballot(mv > 0.5f);
    if (q == 0) s_len2 = (int)__popcll(bal);
    b2[q] = idx2[r * P_ + q] * K_;
  }
  __syncthreads();
  const int len2 = s_len2;
  const int total = s_len1 * len2;

  float m[K_], s[K_];
#pragma unroll
  for (int k = 0; k < K_; k++) { m[k] = -3.0e38f; s[k] = 0.f; }

  for (int i = tid; i < total; i += 512) {
    int p = i / len2;
    int q = i - p * len2;
    const uint4* g4 = (const uint4*)(G + b1[p] + b2[q]);  // 16 bf16 = 32 B
    uint4 w0 = g4[0], w1 = g4[1];
    unsigned int uu[8] = {w0.x, w0.y, w0.z, w0.w, w1.x, w1.y, w1.z, w1.w};
    float z[K_];
#pragma unroll
    for (int h = 0; h < 8; h++) {
      z[2 * h + 0] = __uint_as_float(uu[h] << 16);
      z[2 * h + 1] = __uint_as_float(uu[h] & 0xffff0000u);
    }
#pragma unroll
    for (int k = 0; k < K_; k++) {
      float d = z[k] - m[k];
      float e = __expf(-fabsf(d));
      bool up = d > 0.f;
      s[k] = up ? __fmaf_rn(s[k], e, 1.f) : (s[k] + e);
      m[k] = up ? z[k] : m[k];
    }
  }

#pragma unroll
  for (int off = 1; off < 64; off <<= 1) {
#pragma unroll
    for (int k = 0; k < K_; k++) {
      float mo = __shfl_xor(m[k], off, 64);
      float so = __shfl_xor(s[k], off, 64);
      float d = mo - m[k];
      float e = __expf(-fabsf(d));
      bool up = d > 0.f;
      s[k] = up ? __fmaf_rn(s[k], e, so) : __fmaf_rn(so, e, s[k]);
      m[k] = up ? mo : m[k];
    }
  }
  const int wave = tid >> 6, lane = tid & 63;
  if (lane == 0) {
#pragma unroll
    for (int k = 0; k < K_; k++) { wmx[wave][k] = m[k]; wsum[wave][k] = s[k]; }
  }
  __syncthreads();
  if (tid < K_) {
    float M = -3.0e38f, Ssum = 0.f;
#pragma unroll
    for (int w = 0; w < 8; w++) {
      float mo = wmx[w][tid], so = wsum[w][tid];
      float d = mo - M;
      float e = __expf(-fabsf(d));
      bool up = d > 0.f;
      Ssum = up ? __fmaf_rn(Ssum, e, so) : __fmaf_rn(so, e, Ssum);
      M = up ? mo : M;
    }
    out[r * K_ + tid] = M + __logf(Ssum);
  }
}

// ---------------------------------------------------------------------------
extern "C" void kernel_launch(void* const* d_in, const int* in_sizes, int n_in,
                              void* d_out, int out_size, void* d_ws, size_t ws_size,
                              hipStream_t stream) {
  const float* WE    = (const float*)d_in[0];  // [500][768]
  const float* Wf    = (const float*)d_in[1];  // [768][16][768]
  const int*   idx1  = (const int*)d_in[2];
  const int*   idx2  = (const int*)d_in[3];
  const float* mask1 = (const float*)d_in[4];
  const float* mask2 = (const float*)d_in[5];
  float* out = (float*)d_out;                  // [256][16]

  // workspace: projb [512][12288] bf16 (== [8192][768]) | G [500][500][16]
  // bf16  (~20 MB, 16B-aligned).  No WEb, no prep kernel.
  ushort_t* projb = (ushort_t*)d_ws;
  ushort_t* G     = projb + (size_t)512 * 12288;

  // proj[s][(k,e)] = cvt(WE) @ W : M=512, N=12288, tile 128x128, 384 blocks
  mm0_f<<<dim3(96, 4), 256, 0, stream>>>(WE, Wf, projb);
  // G[(s1,k)][s2] = projb @ cvt(WE)^T : M=8192, N=512, tile 128x64, 512 blocks
  mm1_f<<<dim3(8, 64), 256, 0, stream>>>(projb, WE, G);
  lse_kernel<<<R_, 512, 0, stream>>>(G, idx1, idx2, mask1, mask2, out);
}

// Round 10
// 131.048 us; speedup vs baseline: 3.2554x; 1.1886x over previous
//
#include <hip/hip_runtime.h>
#include <math.h>

// Problem constants
#define S_ 500
#define D_ 768
#define K_ 16
#define R_ 256
#define P_ 64
#define NT 12  // 768 / BK, BK = 64

typedef unsigned short ushort_t;
typedef __attribute__((ext_vector_type(8))) short short8;   // 8 x bf16 (4 VGPRs)
typedef __attribute__((ext_vector_type(4))) float floatx4;  // MFMA accumulator
typedef __attribute__((ext_vector_type(4))) float fx4;      // global fp32 vec load

__device__ inline ushort_t f2bf(float x) {  // fp32 -> bf16, round-nearest-even
  unsigned int u = __float_as_uint(x);
  u += 0x7fffu + ((u >> 16) & 1u);
  return (ushort_t)(u >> 16);
}

// packed fp32x2 -> bf16x2 (RNE), single VALU op
__device__ inline unsigned int cvtpk(float lo, float hi) {
  unsigned int r;
  asm("v_cvt_pk_bf16_f32 %0, %1, %2" : "=v"(r) : "v"(lo), "v"(hi));
  return r;
}

#define GLD_LDS16(g, l)                                                        \
  __builtin_amdgcn_global_load_lds(                                            \
      (const __attribute__((address_space(1))) void*)(g),                      \
      (__attribute__((address_space(3))) void*)(l), 16, 0, 0)

// raw barrier / fine-grained vmcnt (mm1's proven pattern)
#define ASM_BARRIER asm volatile("s_barrier" ::: "memory")
#define WAIT_VM6 asm volatile("s_waitcnt vmcnt(6)" ::: "memory")
#define WAIT_VM0 asm volatile("s_waitcnt vmcnt(0)" ::: "memory")

// mm0's schedule primitives (r5-proven pattern, counts re-derived)
#define CFENCE asm volatile("" ::: "memory")
#define BARRIER_SYNC                                                           \
  do { CFENCE; __builtin_amdgcn_s_barrier(); CFENCE; } while (0)
#define WAIT_VM10_F                                                            \
  do { asm volatile("s_waitcnt vmcnt(10)" ::: "memory");                       \
       __builtin_amdgcn_sched_barrier(0); } while (0)
#define WAIT_VM0_F                                                             \
  do { asm volatile("s_waitcnt vmcnt(0)" ::: "memory");                        \
       __builtin_amdgcn_sched_barrier(0); } while (0)
#define WAIT_LGKM0_F                                                           \
  do { asm volatile("s_waitcnt lgkmcnt(0)" ::: "memory");                      \
       __builtin_amdgcn_sched_barrier(0); } while (0)

// ---------------------------------------------------------------------------
// prep: WE fp32 [500][768] -> WEb bf16 [512][768] (pad rows = 0).  (r5-proven)
// ---------------------------------------------------------------------------
__global__ __launch_bounds__(256) void prep(const float* __restrict__ WE,
                                            ushort_t* __restrict__ WEb) {
  const int t = threadIdx.x;
  int gid = blockIdx.x * 256 + t;  // 98304 threads, 4 elems each
  int row = gid / 192;             // 192 float4 per row
  ushort4 o = {0, 0, 0, 0};
  if (row < S_) {
    float4 v = *(const float4*)(WE + (size_t)gid * 4);
    o.x = f2bf(v.x); o.y = f2bf(v.y); o.z = f2bf(v.z); o.w = f2bf(v.w);
  }
  *(ushort4*)(WEb + (size_t)gid * 4) = o;
}

// ---------------------------------------------------------------------------
// mm0_fused: proj = WEb @ W (fp32 B converted in staging).  RETILED r9->r10:
// 64m x 128n, BK=64 dbuf, 48 KB LDS, grid (96,8) = 768 blocks = EXACTLY
// 3 blocks/CU (was 128x128 @ 384 blocks = 1.5/CU avg, OccupancyPercent 12.7,
// MfmaUtil 6.8 -> latency-bound).  12 waves/CU doubles latency hiding; no
// dispatch tail.  W-panel L2 locality preserved AND all 8 same-x blocks
// co-resident on one XCD (96 blocks/XCD = 32 CU x 3).
// Counted-vmcnt two-barrier schedule (r5-proven pattern): per iter outstanding
// at the wait = A(t)2(oldest) + B(t+1)8 + A(t+1)2 = 12 -> vmcnt(10) retires
// exactly own A(t); 10 stay in flight across both barriers.
// A path: global_load_lds from WEb (linear LDS, 2 issues/thread/iter).
// B path: r5-proven reg-stage 4x4 fp32 blocks, cvt_pk, ds_write_b64 into
// XOR-swizzled Bs (byte ^ ((nq&15)<<4)); read applies the same involution.
// mfma(b,a): lane regs span 4 consecutive C-cols -> ushort4 stores.
// C = proj bf16 [512][12288] (== proj2d [8192][768] in memory).
// ---------------------------------------------------------------------------
__global__ __launch_bounds__(256, 3) void mm0_fused(const ushort_t* __restrict__ A,
                                                    const float* __restrict__ Wf,
                                                    ushort_t* __restrict__ C) {
  __shared__ ushort_t As[2][2][64 * 32];   // [buf][ksub][row][32k'], 16 KB
  __shared__ ushort_t Bs[2][2][128 * 32];  // 32 KB, XOR-swizzled
  const int tid = threadIdx.x;
  const int wave = tid >> 6, lane = tid & 63;
  const int m0 = blockIdx.y * 64, n0 = blockIdx.x * 128;
  const int wn = wave * 32;  // wave owns 64m x 32n
  const int col = lane & 15, quad = lane >> 4;

  floatx4 acc[4][2];
#pragma unroll
  for (int i = 0; i < 4; i++)
#pragma unroll
    for (int j = 0; j < 2; j++)
#pragma unroll
      for (int e = 0; e < 4; e++) acc[i][j][e] = 0.f;

  // --- A staging: 1 gld_lds per 64x32 sub-buffer (256 thr x 16 B = 4 KB) ---
  // thread t: row t>>2 (0..63), 16B slot t&3; wave-uniform LDS base + lane*16
  const ushort_t* ga0 = A + (size_t)(m0 + (tid >> 2)) * D_ + (tid & 3) * 8;
#define ISSUE_A(t_, buf_)                                                      \
  do {                                                                         \
    const ushort_t* ga = ga0 + (t_)*64;                                        \
    GLD_LDS16(ga, &As[buf_][0][wave * 512]);                                   \
    GLD_LDS16(ga + 32, &As[buf_][1][wave * 512]);                              \
  } while (0)

  // --- B staging: thread owns 4x4 fp32 blocks (dqA, nq) h=0 and (dqA+8, nq)
  const int nq = tid & 31;   // row-quad 0..31: rows nq*4+j
  const int dqA = tid >> 5;  // k-quad 0..7:  k'' = dqA*4 + i (h=0); +32 (h=1)
  const float* gwA = Wf + (size_t)(dqA * 4) * 12288 + n0 + nq * 4;
  const float* gwB = gwA + (size_t)32 * 12288;

  fx4 bv[2][4];
#define LOADB(t_)                                                              \
  do {                                                                         \
    _Pragma("unroll") for (int i = 0; i < 4; i++) {                            \
      bv[0][i] = *(const fx4*)(gwA + (size_t)((t_)*64 + i) * 12288);           \
      bv[1][i] = *(const fx4*)(gwB + (size_t)((t_)*64 + i) * 12288);           \
    }                                                                          \
  } while (0)

  // Bs[sub][row n][k'' 0..31] bf16 (row stride 64 B), byte ^ ((nq&15)<<4)
#define WRITEB(buf_)                                                           \
  do {                                                                         \
    _Pragma("unroll") for (int h = 0; h < 2; h++)                              \
    _Pragma("unroll") for (int j = 0; j < 4; j++) {                            \
      int row = nq * 4 + j;                                                    \
      uint2 w;                                                                 \
      w.x = cvtpk(bv[h][0][j], bv[h][1][j]);                                   \
      w.y = cvtpk(bv[h][2][j], bv[h][3][j]);                                   \
      *(uint2*)((char*)&Bs[buf_][h][0] +                                       \
                ((row * 64 + dqA * 8) ^ ((nq & 15) << 4))) = w;                \
    }                                                                          \
  } while (0)

  // prologue: bv(0) issued BEFORE A(0) so WRITEB's compiler wait is vmcnt(2)
  // and A(0) stays in flight; lgkmcnt(0) publishes Bs[0] pre-barrier.
  LOADB(0);
  ISSUE_A(0, 0);
  WRITEB(0);
  WAIT_LGKM0_F;
  // loop invariant at iter t entry: own outstanding vmem = A(t)'s 2 gld_lds.
  for (int t = 0; t < NT; ++t) {
    const int cur = t & 1;
    if (t + 1 < NT) {
      LOADB(t + 1);             // +8
      ISSUE_A(t + 1, cur ^ 1);  // +2 -> outstanding = A(t)2(oldest) + 10
      WAIT_VM10_F;              // FIFO retire: drains exactly own A(t)
    } else {
      WAIT_VM0_F;
    }
    BARRIER_SYNC;  // collective: all waves' tile-t A landed; Bs[cur] written
#pragma unroll
    for (int s = 0; s < 2; ++s) {
      short8 a[4], b[2];
#pragma unroll
      for (int i = 0; i < 4; i++)
        a[i] = *(const short8*)&As[cur][s][(i * 16 + col) * 32 + quad * 8];
#pragma unroll
      for (int j = 0; j < 2; j++) {
        int row = wn + j * 16 + col;
        b[j] = *(const short8*)((const char*)&Bs[cur][s][0] +
                                ((row * 64 + quad * 16) ^ (((row >> 2) & 15) << 4)));
      }
#pragma unroll
      for (int i = 0; i < 4; i++)
#pragma unroll
        for (int j = 0; j < 2; j++)
          acc[i][j] = __builtin_amdgcn_mfma_f32_16x16x32_bf16(b[j], a[i], acc[i][j], 0, 0, 0);
    }
    if (t + 1 < NT) {
      WRITEB(cur ^ 1);  // compiler vmcnt(2) for bv(t+1); A(t+1) stays flying
      WAIT_LGKM0_F;     // publish ds_writes before releasing readers
    }
    BARRIER_SYNC;  // separates compute(t) readers from iter-t+1 buf writers
  }
#undef ISSUE_A
#undef LOADB
#undef WRITEB

#pragma unroll
  for (int i = 0; i < 4; i++) {
    int m = m0 + i * 16 + col;
#pragma unroll
    for (int j = 0; j < 2; j++) {
      int n = n0 + wn + j * 16 + quad * 4;
      ushort4 o;
      o.x = f2bf(acc[i][j][0]); o.y = f2bf(acc[i][j][1]);
      o.z = f2bf(acc[i][j][2]); o.w = f2bf(acc[i][j][3]);
      *(ushort4*)(C + (size_t)m * 12288 + n) = o;
    }
  }
}

// ---------------------------------------------------------------------------
// mm1_bt: G = projb @ WEb^T.  (r5-proven, unchanged.)  Tile 128m x 64n,
// BK=64 dbuf, 48 KB LDS; grid 8x64 = 512 = 2/CU exact.  XCD-aware bijective
// remap: same-yb blocks share one A-panel on one XCD.
// mfma(a,b): lane regs span k (G's contiguous dim) -> ushort4 scatter into
// bf16 G[s1][s2][16], guarded < 500.
// ---------------------------------------------------------------------------
__global__ __launch_bounds__(256, 2) void mm1_bt(const ushort_t* __restrict__ A,
                                                 const ushort_t* __restrict__ Bm,
                                                 ushort_t* __restrict__ G) {
  __shared__ ushort_t As[2][2][128 * 32];  // 32 KB
  __shared__ ushort_t Bs[2][2][64 * 32];   // 16 KB
  const int tid = threadIdx.x;
  const int wave = tid >> 6, lane = tid & 63;
  // lin bits [b8..b0]: yb = {b2 b1 b0 b8 b7 b6}, xb = {b5 b4 b3}
  const int lin = blockIdx.x + (blockIdx.y << 3);
  const int yb = ((lin & 7) << 3) | (lin >> 6);
  const int xb = (lin >> 3) & 7;
  const int m0 = yb * 128, n0 = xb * 64;
  const int wm = (wave & 1) * 64, wn = (wave >> 1) * 32;
  const int col = lane & 15, quad = lane >> 4;

  floatx4 acc[4][2];
#pragma unroll
  for (int i = 0; i < 4; i++)
#pragma unroll
    for (int j = 0; j < 2; j++)
#pragma unroll
      for (int e = 0; e < 4; e++) acc[i][j][e] = 0.f;

  const int lrow = lane >> 2, scol = (lane & 3) * 8;
  const ushort_t* ga0 = A + (size_t)(m0 + wave * 32 + lrow) * D_ + scol;
  const ushort_t* gb0 = Bm + (size_t)(n0 + wave * 16 + lrow) * D_ + scol;
  const int aoff = (wave * 32) * 32;
  const int boff = (wave * 16) * 32;

#define ISSUE_TILE1(t_, buf_)                                                  \
  do {                                                                         \
    _Pragma("unroll") for (int s_ = 0; s_ < 2; s_++) {                         \
      const ushort_t* ga = ga0 + (t_)*64 + s_ * 32;                            \
      const ushort_t* gb = gb0 + (t_)*64 + s_ * 32;                            \
      GLD_LDS16(ga, &As[buf_][s_][aoff]);                                      \
      GLD_LDS16(ga + 16 * D_, &As[buf_][s_][aoff + 16 * 32]);                  \
      GLD_LDS16(gb, &Bs[buf_][s_][boff]);                                      \
    }                                                                          \
  } while (0)

  ISSUE_TILE1(0, 0);
  for (int t = 0; t < NT; ++t) {
    const int cur = t & 1;
    if (t + 1 < NT) {
      ISSUE_TILE1(t + 1, cur ^ 1);
      WAIT_VM6;
    } else {
      WAIT_VM0;
    }
    ASM_BARRIER;
#pragma unroll
    for (int s = 0; s < 2; ++s) {
      short8 a[4], b[2];
#pragma unroll
      for (int i = 0; i < 4; i++)
        a[i] = *(const short8*)&As[cur][s][(wm + i * 16 + col) * 32 + quad * 8];
#pragma unroll
      for (int j = 0; j < 2; j++)
        b[j] = *(const short8*)&Bs[cur][s][(wn + j * 16 + col) * 32 + quad * 8];
#pragma unroll
      for (int i = 0; i < 4; i++)
#pragma unroll
        for (int j = 0; j < 2; j++)
          acc[i][j] = __builtin_amdgcn_mfma_f32_16x16x32_bf16(a[i], b[j], acc[i][j], 0, 0, 0);
    }
    ASM_BARRIER;
  }
#undef ISSUE_TILE1

  // G[s1][s2][16] bf16: m = (s1,k); 16x16 m-tile is one s1, k = quad*4+reg
#pragma unroll
  for (int i = 0; i < 4; i++) {
    int s1 = (m0 + wm + i * 16) >> 4;
#pragma unroll
    for (int j = 0; j < 2; j++) {
      int s2 = n0 + wn + j * 16 + col;
      if (s1 < S_ && s2 < S_) {
        ushort4 o;
        o.x = f2bf(acc[i][j][0]); o.y = f2bf(acc[i][j][1]);
        o.z = f2bf(acc[i][j][2]); o.w = f2bf(acc[i][j][3]);
        *(ushort4*)(G + (((size_t)s1 * S_ + s2) << 4) + quad * 4) = o;
      }
    }
  }
}

// ---------------------------------------------------------------------------
// lse_kernel: out[r][k] = logsumexp over valid (p,q) of G[idx1[r,p]][idx2[r,q]][k]
// One block per r; 512 threads; 1-exp online update.  (r5-proven, unchanged.)
// ---------------------------------------------------------------------------
__global__ __launch_bounds__(512) void lse_kernel(const ushort_t* __restrict__ G,
                                                  const int* __restrict__ idx1,
                                                  const int* __restrict__ idx2,
                                                  const float* __restrict__ mask1,
                                                  const float* __restrict__ mask2,
                                                  float* __restrict__ out) {
  const int r = blockIdx.x;
  const int tid = threadIdx.x;
  __shared__ int b1[P_], b2[P_];
  __shared__ int s_len1, s_len2;
  __shared__ float wmx[8][K_], wsum[8][K_];

  if (tid < 64) {
    float mv = mask1[r * P_ + tid];
    unsigned long long bal = __ballot(mv > 0.5f);
    if (tid == 0) s_len1 = (int)__popcll(bal);
    b1[tid] = idx1[r * P_ + tid] * (S_ * K_);
  } else if (tid < 128) {
    int q = tid - 64;
    float mv = mask2[r * P_ + q];
    unsigned long long bal = __ballot(mv > 0.5f);
    if (q == 0) s_len2 = (int)__popcll(bal);
    b2[q] = idx2[r * P_ + q] * K_;
  }
  __syncthreads();
  const int len2 = s_len2;
  const int total = s_len1 * len2;

  float m[K_], s[K_];
#pragma unroll
  for (int k = 0; k < K_; k++) { m[k] = -3.0e38f; s[k] = 0.f; }

  for (int i = tid; i < total; i += 512) {
    int p = i / len2;
    int q = i - p * len2;
    const uint4* g4 = (const uint4*)(G + b1[p] + b2[q]);  // 16 bf16 = 32 B
    uint4 w0 = g4[0], w1 = g4[1];
    unsigned int uu[8] = {w0.x, w0.y, w0.z, w0.w, w1.x, w1.y, w1.z, w1.w};
    float z[K_];
#pragma unroll
    for (int h = 0; h < 8; h++) {
      z[2 * h + 0] = __uint_as_float(uu[h] << 16);
      z[2 * h + 1] = __uint_as_float(uu[h] & 0xffff0000u);
    }
#pragma unroll
    for (int k = 0; k < K_; k++) {
      float d = z[k] - m[k];
      float e = __expf(-fabsf(d));
      bool up = d > 0.f;
      s[k] = up ? __fmaf_rn(s[k], e, 1.f) : (s[k] + e);
      m[k] = up ? z[k] : m[k];
    }
  }

#pragma unroll
  for (int off = 1; off < 64; off <<= 1) {
#pragma unroll
    for (int k = 0; k < K_; k++) {
      float mo = __shfl_xor(m[k], off, 64);
      float so = __shfl_xor(s[k], off, 64);
      float d = mo - m[k];
      float e = __expf(-fabsf(d));
      bool up = d > 0.f;
      s[k] = up ? __fmaf_rn(s[k], e, so) : __fmaf_rn(so, e, s[k]);
      m[k] = up ? mo : m[k];
    }
  }
  const int wave = tid >> 6, lane = tid & 63;
  if (lane == 0) {
#pragma unroll
    for (int k = 0; k < K_; k++) { wmx[wave][k] = m[k]; wsum[wave][k] = s[k]; }
  }
  __syncthreads();
  if (tid < K_) {
    float M = -3.0e38f, Ssum = 0.f;
#pragma unroll
    for (int w = 0; w < 8; w++) {
      float mo = wmx[w][tid], so = wsum[w][tid];
      float d = mo - M;
      float e = __expf(-fabsf(d));
      bool up = d > 0.f;
      Ssum = up ? __fmaf_rn(Ssum, e, so) : __fmaf_rn(so, e, Ssum);
      M = up ? mo : M;
    }
    out[r * K_ + tid] = M + __logf(Ssum);
  }
}

// ---------------------------------------------------------------------------
extern "C" void kernel_launch(void* const* d_in, const int* in_sizes, int n_in,
                              void* d_out, int out_size, void* d_ws, size_t ws_size,
                              hipStream_t stream) {
  const float* WE    = (const float*)d_in[0];  // [500][768]
  const float* Wf    = (const float*)d_in[1];  // [768][16][768]
  const int*   idx1  = (const int*)d_in[2];
  const int*   idx2  = (const int*)d_in[3];
  const float* mask1 = (const float*)d_in[4];
  const float* mask2 = (const float*)d_in[5];
  float* out = (float*)d_out;                  // [256][16]

  // workspace: WEb [512][768] bf16 | projb [512][12288] bf16 (== [8192][768])
  //            | G [500][500][16] bf16   (~21.4 MB total, 16B-aligned)
  ushort_t* WEb   = (ushort_t*)d_ws;
  ushort_t* projb = WEb + (size_t)512 * 768;
  ushort_t* G     = projb + (size_t)512 * 12288;

  prep<<<384, 256, 0, stream>>>(WE, WEb);
  // proj[s][(k,e)] = WEb @ W : M=512, N=12288, tile 64x128, 768 blocks = 3/CU
  mm0_fused<<<dim3(96, 8), 256, 0, stream>>>(WEb, Wf, projb);
  // G[(s1,k)][s2] = projb @ WEb^T : M=8192, N=512, tile 128x64, 512 blocks
  mm1_bt<<<dim3(8, 64), 256, 0, stream>>>(projb, WEb, G);
  lse_kernel<<<R_, 512, 0, stream>>>(G, idx1, idx2, mask1, mask2, out);
}